// Round 1
// baseline (774.548 us; speedup 1.0000x reference)
//
#include <hip/hip_runtime.h>
#include <math.h>

#define NTOK   16384
#define DIM    4096
#define NEXP   256
#define NGRP   8
#define TOPKG  4
#define TOPK   8

// ---------------- GEMM: logits[T,E] = X[T,D] * W[E,D]^T (fp32) ----------------
#define BM 64
#define BN 64
#define BK 16
#define PAD 4

__global__ __launch_bounds__(256) void gate_gemm(const float* __restrict__ X,
                                                 const float* __restrict__ W,
                                                 float* __restrict__ L) {
    __shared__ float As[BK][BM + PAD];
    __shared__ float Bs[BK][BN + PAD];
    const int t  = threadIdx.x;
    const int bm = blockIdx.y * BM;
    const int bn = blockIdx.x * BN;
    const int lm = t >> 2;          // 0..63: row within tile to load
    const int lk = (t & 3) * 4;     // 0,4,8,12: k-offset of the float4
    const int tx = t & 15;          // 0..15: output col quad
    const int ty = t >> 4;          // 0..15: output row quad

    const float* xa = X + (size_t)(bm + lm) * DIM + lk;
    const float* wb = W + (size_t)(bn + lm) * DIM + lk;

    float acc[4][4] = {};

    for (int k0 = 0; k0 < DIM; k0 += BK) {
        float4 av = *(const float4*)(xa + k0);
        float4 bv = *(const float4*)(wb + k0);
        __syncthreads();            // previous iter's reads must finish
        As[lk + 0][lm] = av.x; As[lk + 1][lm] = av.y;
        As[lk + 2][lm] = av.z; As[lk + 3][lm] = av.w;
        Bs[lk + 0][lm] = bv.x; Bs[lk + 1][lm] = bv.y;
        Bs[lk + 2][lm] = bv.z; Bs[lk + 3][lm] = bv.w;
        __syncthreads();
#pragma unroll
        for (int k = 0; k < BK; ++k) {
            float4 a = *(const float4*)&As[k][ty * 4];
            float4 b = *(const float4*)&Bs[k][tx * 4];
            const float ar[4] = {a.x, a.y, a.z, a.w};
            const float br[4] = {b.x, b.y, b.z, b.w};
#pragma unroll
            for (int i = 0; i < 4; ++i)
#pragma unroll
                for (int j = 0; j < 4; ++j)
                    acc[i][j] = fmaf(ar[i], br[j], acc[i][j]);
        }
    }

#pragma unroll
    for (int i = 0; i < 4; ++i) {
        float4 o = {acc[i][0], acc[i][1], acc[i][2], acc[i][3]};
        *(float4*)&L[(size_t)(bm + ty * 4 + i) * NEXP + bn + tx * 4] = o;
    }
}

// ---------------- Routing: one wave (64 lanes) per token ----------------
// lane holds experts 4*lane .. 4*lane+3; group = lane>>3 (8 lanes/group of 32)
__global__ __launch_bounds__(256) void gate_route(const float* __restrict__ L,
                                                  float* __restrict__ outw,
                                                  float* __restrict__ outi) {
    const int lane = threadIdx.x & 63;
    const int tok  = (blockIdx.x * blockDim.x + threadIdx.x) >> 6;
    if (tok >= NTOK) return;

    const float* row = L + (size_t)tok * NEXP;
    float4 v = *(const float4*)(row + lane * 4);
    float l[4] = {v.x, v.y, v.z, v.w};

    // wave-wide max logit
    float lmax = fmaxf(fmaxf(l[0], l[1]), fmaxf(l[2], l[3]));
    float m = lmax;
#pragma unroll
    for (int o = 32; o; o >>= 1) m = fmaxf(m, __shfl_xor(m, o));

    // softmax denominator over ALL 256 experts
    float s = __expf(l[0] - m) + __expf(l[1] - m) + __expf(l[2] - m) + __expf(l[3] - m);
#pragma unroll
    for (int o = 32; o; o >>= 1) s += __shfl_xor(s, o);

    // per-group max logit (monotone proxy for max softmax score)
    float gm = lmax;
#pragma unroll
    for (int o = 4; o; o >>= 1) gm = fmaxf(gm, __shfl_xor(gm, o));

    // rank my group among the 8 group maxes (ties -> lower group index wins)
    const int g = lane >> 3;
    int rank = 0;
#pragma unroll
    for (int gg = 0; gg < 8; ++gg) {
        float vg = __shfl(gm, gg * 8);
        rank += (vg > gm) || (vg == gm && gg < g);
    }
    const bool allowed = rank < TOPKG;

    float mv[4];
#pragma unroll
    for (int j = 0; j < 4; ++j) mv[j] = allowed ? l[j] : -INFINITY;

    float wsel = 0.0f;
    int   isel = 0;

    for (int k = 0; k < TOPK; ++k) {
        // local argmax among this lane's 4 (tie -> lower index via strict >)
        float bv = mv[0];
        int   bi = lane * 4;
        if (mv[1] > bv) { bv = mv[1]; bi = lane * 4 + 1; }
        if (mv[2] > bv) { bv = mv[2]; bi = lane * 4 + 2; }
        if (mv[3] > bv) { bv = mv[3]; bi = lane * 4 + 3; }
        // wave argmax with (value desc, index asc) lexicographic order
#pragma unroll
        for (int o = 32; o; o >>= 1) {
            float ov = __shfl_xor(bv, o);
            int   oi = __shfl_xor(bi, o);
            if (ov > bv || (ov == bv && oi < bi)) { bv = ov; bi = oi; }
        }
        if (lane == k) { wsel = __expf(bv - m) / s; isel = bi; }
        if ((bi >> 2) == lane) mv[bi & 3] = -INFINITY;  // remove selected
    }

    if (lane < TOPK) {
        outw[(size_t)tok * TOPK + lane] = wsel;
        outi[(size_t)tok * TOPK + lane] = (float)isel;
    }
}

extern "C" void kernel_launch(void* const* d_in, const int* in_sizes, int n_in,
                              void* d_out, int out_size, void* d_ws, size_t ws_size,
                              hipStream_t stream) {
    const float* x = (const float*)d_in[0];   // [16384, 4096]
    const float* w = (const float*)d_in[1];   // [256, 4096]
    float* logits  = (float*)d_ws;            // [16384, 256] = 16 MB
    float* outw    = (float*)d_out;                     // [16384, 8] weights
    float* outi    = (float*)d_out + (size_t)NTOK * TOPK; // [16384, 8] idx (as float)

    dim3 ggrid(NEXP / BN, NTOK / BM);   // (4, 256)
    gate_gemm<<<ggrid, 256, 0, stream>>>(x, w, logits);

    int rblocks = (NTOK * 64) / 256;    // 4096 blocks, 4 waves each
    gate_route<<<rblocks, 256, 0, stream>>>(logits, outw, outi);
}